// Round 5
// baseline (1213.562 us; speedup 1.0000x reference)
//
#include <hip/hip_runtime.h>
#include <hip/hip_bf16.h>
#include <math.h>

#define D 256
#define DOUT 40
#define HB 32   // private-histogram blocks

typedef __attribute__((ext_vector_type(8))) short short8;
typedef __attribute__((ext_vector_type(4))) float f32x4;

__device__ __forceinline__ float lo_bf(unsigned w) {
    union { unsigned u; float f; } c; c.u = w << 16; return c.f;
}
__device__ __forceinline__ float hi_bf(unsigned w) {
    union { unsigned u; float f; } c; c.u = w & 0xffff0000u; return c.f;
}
__device__ __forceinline__ float b2f(unsigned short u) {
    union { unsigned u; float f; } c; c.u = ((unsigned)u) << 16; return c.f;
}
__device__ __forceinline__ unsigned short f2b(float f) {
    __hip_bfloat16 h = __float2bfloat16(f);   // RNE
    return reinterpret_cast<unsigned short&>(h);
}

// ---------------- per-block private histograms (workgroup-scope atomics) ----------------
// Each block owns inH[b][N], outH[b][N]; atomics stay XCD-L2-resident (no device scope).
__global__ __launch_bounds__(1024) void k_hist(const int* __restrict__ src,
                                               const int* __restrict__ dst,
                                               unsigned* __restrict__ inH,
                                               unsigned* __restrict__ outH,
                                               int n, int E) {
    unsigned* myIn  = inH  + (size_t)blockIdx.x * n;
    unsigned* myOut = outH + (size_t)blockIdx.x * n;
    for (int i = threadIdx.x; i < n; i += 1024) { myIn[i] = 0u; myOut[i] = 0u; }
    __syncthreads();
    int per = (E + HB - 1) / HB;
    int lo = blockIdx.x * per;
    int hi = min(E, lo + per);
    for (int e = lo + threadIdx.x; e < hi; e += 1024) {
        int d = __builtin_nontemporal_load(dst + e);
        int s = __builtin_nontemporal_load(src + e);
        __hip_atomic_fetch_add(&myIn[d], 1u, __ATOMIC_RELAXED, __HIP_MEMORY_SCOPE_WORKGROUP);
        __hip_atomic_fetch_add(&myOut[s], 1u, __ATOMIC_RELAXED, __HIP_MEMORY_SCOPE_WORKGROUP);
    }
}

// ---------------- column reduce: degrees, inv-sqrt, per-block exclusive prefixes ----------------
__global__ __launch_bounds__(256) void k_colred(unsigned* __restrict__ inH,
                                                const unsigned* __restrict__ outH,
                                                int* __restrict__ indeg,
                                                float* __restrict__ inv_in,
                                                float* __restrict__ inv_out, int n) {
    int i = blockIdx.x * 256 + threadIdx.x;
    if (i >= n) return;
    unsigned accI = 0, accO = 0;
    #pragma unroll 4
    for (int b = 0; b < HB; ++b) {
        size_t idx = (size_t)b * n + i;
        unsigned t = inH[idx];
        inH[idx] = accI;          // exclusive prefix (becomes scatter cursor base)
        accI += t;
        accO += outH[idx];
    }
    indeg[i] = (int)accI;
    inv_in[i]  = accI ? rsqrtf((float)accI) : 0.f;
    inv_out[i] = accO ? rsqrtf((float)accO) : 0.f;
}

// ---------------- hierarchical exclusive scan ----------------
__global__ __launch_bounds__(1024) void k_scan1(const int* __restrict__ deg,
                                                int* __restrict__ offs,
                                                int* __restrict__ bsum, int n) {
    __shared__ int wsum[16];
    int tid = threadIdx.x, lane = tid & 63, wv = tid >> 6;
    int i = blockIdx.x * 1024 + tid;
    int v = (i < n) ? deg[i] : 0;
    int x = v;
    #pragma unroll
    for (int o = 1; o < 64; o <<= 1) {
        int t = __shfl_up(x, o);
        if (lane >= o) x += t;
    }
    if (lane == 63) wsum[wv] = x;
    __syncthreads();
    if (wv == 0 && lane < 16) {
        int y = wsum[lane];
        #pragma unroll
        for (int o = 1; o < 16; o <<= 1) {
            int t = __shfl_up(y, o);
            if (lane >= o) y += t;
        }
        wsum[lane] = y;
    }
    __syncthreads();
    int waveoff = wv ? wsum[wv - 1] : 0;
    if (i < n) offs[i] = waveoff + x - v;
    if (tid == 0) bsum[blockIdx.x] = wsum[15];
}

__global__ __launch_bounds__(64) void k_scan2(int* __restrict__ bsum, int G) {
    int lane = threadIdx.x;
    int carry = 0;
    for (int base = 0; base < G; base += 64) {
        int idx = base + lane;
        int v = (idx < G) ? bsum[idx] : 0;
        int x = v;
        #pragma unroll
        for (int o = 1; o < 64; o <<= 1) {
            int t = __shfl_up(x, o);
            if (lane >= o) x += t;
        }
        int tot = __shfl(x, 63);
        if (idx < G) bsum[idx] = carry + x - v;
        carry += tot;
    }
}

__global__ __launch_bounds__(1024) void k_scan3(int* __restrict__ offs,
                                                const int* __restrict__ bsum,
                                                int n, int E) {
    int i = blockIdx.x * 1024 + threadIdx.x;
    if (i < n) offs[i] += bsum[blockIdx.x];
    if (i == 0) offs[n] = E;
}

// ---------------- scatter using per-block prefix cursors (workgroup-scope) ----------------
__global__ __launch_bounds__(1024) void k_scatter2(const int* __restrict__ src,
                                                   const int* __restrict__ dst,
                                                   const int* __restrict__ offs,
                                                   unsigned* __restrict__ inH,
                                                   const float* __restrict__ inv_out,
                                                   int* __restrict__ csr_src,
                                                   float* __restrict__ csr_w,
                                                   int n, int E) {
    unsigned* myCur = inH + (size_t)blockIdx.x * n;
    int per = (E + HB - 1) / HB;
    int lo = blockIdx.x * per;
    int hi = min(E, lo + per);
    for (int e = lo + threadIdx.x; e < hi; e += 1024) {
        int d = __builtin_nontemporal_load(dst + e);
        int s = __builtin_nontemporal_load(src + e);
        unsigned r = __hip_atomic_fetch_add(&myCur[d], 1u, __ATOMIC_RELAXED,
                                            __HIP_MEMORY_SCOPE_WORKGROUP);
        int idx = offs[d] + (int)r;
        __builtin_nontemporal_store(s, &csr_src[idx]);
        __builtin_nontemporal_store(inv_out[s], &csr_w[idx]);
    }
}

// ---------------- f32 -> bf16 conversion (x) ----------------
__global__ __launch_bounds__(256) void k_cvt_x(const float* __restrict__ in,
                                               unsigned short* __restrict__ out,
                                               long long n8) {
    long long i = (long long)blockIdx.x * 256 + threadIdx.x;
    if (i >= n8) return;
    const float4* p = reinterpret_cast<const float4*>(in) + i * 2;
    float4 a = p[0], b = p[1];
    uint4 o;
    o.x = (unsigned)f2b(a.x) | ((unsigned)f2b(a.y) << 16);
    o.y = (unsigned)f2b(a.z) | ((unsigned)f2b(a.w) << 16);
    o.z = (unsigned)f2b(b.x) | ((unsigned)f2b(b.y) << 16);
    o.w = (unsigned)f2b(b.z) | ((unsigned)f2b(b.w) << 16);
    reinterpret_cast<uint4*>(out)[i] = o;
}

// ---------------- W[256,256] f32 -> Wt[n][k] bf16 ----------------
__global__ __launch_bounds__(256) void k_cvt_wt(const float* __restrict__ W,
                                                unsigned short* __restrict__ Wt) {
    int n = blockIdx.x, k = threadIdx.x;
    Wt[n * 256 + k] = f2b(W[k * 256 + n]);
}

// ---------------- W3[256,40] f32 -> Wt3[64 pad][256] bf16 ----------------
__global__ __launch_bounds__(256) void k_cvt_wt3(const float* __restrict__ W3,
                                                 unsigned short* __restrict__ Wt3) {
    int n = blockIdx.x, k = threadIdx.x;
    float v = (n < DOUT) ? W3[k * DOUT + n] : 0.0f;
    Wt3[n * 256 + k] = f2b(v);
}

// ---------------- SpMM bf16, D=256: one wave per dst node, 8 edges in flight ----------------
__global__ __launch_bounds__(256) void k_spmm256b(const unsigned short* __restrict__ h,
                                                  const int* __restrict__ offs,
                                                  const int* __restrict__ csr_src,
                                                  const float* __restrict__ csr_w,
                                                  const float* __restrict__ inv_in,
                                                  unsigned short* __restrict__ out, int n) {
    int wid = (blockIdx.x * 256 + threadIdx.x) >> 6;
    int lane = threadIdx.x & 63;
    if (wid >= n) return;
    int beg = offs[wid], end = offs[wid + 1];
    float a0 = 0.f, a1 = 0.f, a2 = 0.f, a3 = 0.f;
    int j = beg;
    for (; j + 8 <= end; j += 8) {
        int s[8]; float w[8]; uint2 v[8];
        #pragma unroll
        for (int q = 0; q < 8; ++q) { s[q] = csr_src[j + q]; w[q] = csr_w[j + q]; }
        #pragma unroll
        for (int q = 0; q < 8; ++q)
            v[q] = reinterpret_cast<const uint2*>(h + (size_t)s[q] * D)[lane];
        #pragma unroll
        for (int q = 0; q < 8; ++q) {
            a0 += w[q] * lo_bf(v[q].x); a1 += w[q] * hi_bf(v[q].x);
            a2 += w[q] * lo_bf(v[q].y); a3 += w[q] * hi_bf(v[q].y);
        }
    }
    for (; j < end; ++j) {
        int s = csr_src[j];
        float w = csr_w[j];
        uint2 v = reinterpret_cast<const uint2*>(h + (size_t)s * D)[lane];
        a0 += w * lo_bf(v.x); a1 += w * hi_bf(v.x); a2 += w * lo_bf(v.y); a3 += w * hi_bf(v.y);
    }
    float sc = inv_in[wid];
    uint2 r;
    r.x = (unsigned)f2b(sc * a0) | ((unsigned)f2b(sc * a1) << 16);
    r.y = (unsigned)f2b(sc * a2) | ((unsigned)f2b(sc * a3) << 16);
    reinterpret_cast<uint2*>(out + (size_t)wid * D)[lane] = r;
}

// ---------------- bf16 MFMA GEMM: C[M,256] = relu(A[M,256] @ Wt^T + b) ----------------
__global__ __launch_bounds__(256) void k_gemm_mfma(const unsigned short* __restrict__ A,
                                                   const unsigned short* __restrict__ Wt,
                                                   const float* __restrict__ bias,
                                                   unsigned short* __restrict__ C, int M) {
    __shared__ unsigned short As[128][40];
    __shared__ unsigned short Bs[128][40];
    int tid = threadIdx.x;
    int lane = tid & 63, wave = tid >> 6;
    int wr = wave >> 1, wc = wave & 1;
    int rowBase = blockIdx.x * 128;
    int colBase = blockIdx.y * 128;

    f32x4 acc[4][4];
    #pragma unroll
    for (int m = 0; m < 4; ++m)
        #pragma unroll
        for (int n = 0; n < 4; ++n) acc[m][n] = (f32x4){0.f, 0.f, 0.f, 0.f};

    int ar = lane & 15, kg = lane >> 4;

    for (int k0 = 0; k0 < 256; k0 += 32) {
        #pragma unroll
        for (int hh = 0; hh < 2; ++hh) {
            int c = tid + hh * 256;
            int row = c >> 2, kc = c & 3;
            int grow = rowBase + row;
            uint4 v = make_uint4(0, 0, 0, 0);
            if (grow < M)
                v = *reinterpret_cast<const uint4*>(A + (size_t)grow * 256 + k0 + kc * 8);
            *reinterpret_cast<uint4*>(&As[row][kc * 8]) = v;
        }
        #pragma unroll
        for (int hh = 0; hh < 2; ++hh) {
            int c = tid + hh * 256;
            int col = c >> 2, kc = c & 3;
            uint4 v = *reinterpret_cast<const uint4*>(Wt + (size_t)(colBase + col) * 256 + k0 + kc * 8);
            *reinterpret_cast<uint4*>(&Bs[col][kc * 8]) = v;
        }
        __syncthreads();
        short8 a[4], b[4];
        #pragma unroll
        for (int m = 0; m < 4; ++m)
            a[m] = *reinterpret_cast<const short8*>(&As[wr * 64 + m * 16 + ar][kg * 8]);
        #pragma unroll
        for (int n = 0; n < 4; ++n)
            b[n] = *reinterpret_cast<const short8*>(&Bs[wc * 64 + n * 16 + ar][kg * 8]);
        #pragma unroll
        for (int m = 0; m < 4; ++m)
            #pragma unroll
            for (int n = 0; n < 4; ++n)
                acc[m][n] = __builtin_amdgcn_mfma_f32_16x16x32_bf16(a[m], b[n], acc[m][n], 0, 0, 0);
        __syncthreads();
    }

    int rq = lane >> 4, cl = lane & 15;
    float bv[4];
    #pragma unroll
    for (int n = 0; n < 4; ++n) bv[n] = bias[colBase + wc * 64 + n * 16 + cl];
    #pragma unroll
    for (int m = 0; m < 4; ++m) {
        #pragma unroll
        for (int n = 0; n < 4; ++n) {
            int col = colBase + wc * 64 + n * 16 + cl;
            #pragma unroll
            for (int r = 0; r < 4; ++r) {
                int row = rowBase + wr * 64 + m * 16 + rq * 4 + r;
                if (row < M)
                    C[(size_t)row * 256 + col] = f2b(fmaxf(acc[m][n][r] + bv[n], 0.f));
            }
        }
    }
}

// ---------------- fused layers 2+3: z[M,40] = relu(A@W2t^T + b2) @ W3 ----------------
// 512 threads = 8 waves. Stage 1: 128x256 h-tile (relu+bias) -> LDS bf16.
// Stage 2: h-tile @ W3 (LDS-resident) -> z bf16 [M][DOUT].
__global__ __launch_bounds__(512) void k_gemm_fuse23(const unsigned short* __restrict__ A,
                                                     const unsigned short* __restrict__ Wt2,
                                                     const float* __restrict__ b2,
                                                     const unsigned short* __restrict__ Wt3,
                                                     unsigned short* __restrict__ Z, int M) {
    __shared__ unsigned short As[128][40];
    __shared__ unsigned short Bs[256][40];
    __shared__ unsigned short hS[128][264];
    __shared__ unsigned short W3s[64][264];
    int tid = threadIdx.x;
    int lane = tid & 63, wave = tid >> 6;
    int wr = wave >> 2, wc = wave & 3;        // stage-1: 2x4 wave grid over 128x256
    int rowBase = blockIdx.x * 128;
    int ar = lane & 15, kg = lane >> 4;

    // stage W3 once: 64 rows x 256 k
    for (int c = tid; c < 2048; c += 512) {
        int row = c >> 5, kc = c & 31;
        *reinterpret_cast<uint4*>(&W3s[row][kc * 8]) =
            *reinterpret_cast<const uint4*>(Wt3 + (size_t)row * 256 + kc * 8);
    }

    f32x4 acc[4][4];
    #pragma unroll
    for (int m = 0; m < 4; ++m)
        #pragma unroll
        for (int n = 0; n < 4; ++n) acc[m][n] = (f32x4){0.f, 0.f, 0.f, 0.f};

    for (int k0 = 0; k0 < 256; k0 += 32) {
        {   // A panel: 128 rows x 32 k, 512 chunks of 16B
            int row = tid >> 2, kc = tid & 3;
            int grow = rowBase + row;
            uint4 v = make_uint4(0, 0, 0, 0);
            if (grow < M)
                v = *reinterpret_cast<const uint4*>(A + (size_t)grow * 256 + k0 + kc * 8);
            *reinterpret_cast<uint4*>(&As[row][kc * 8]) = v;
        }
        #pragma unroll
        for (int hh = 0; hh < 2; ++hh) {  // B panel: all 256 weight-cols x 32 k
            int c = tid + hh * 512;
            int col = c >> 2, kc = c & 3;
            uint4 v = *reinterpret_cast<const uint4*>(Wt2 + (size_t)col * 256 + k0 + kc * 8);
            *reinterpret_cast<uint4*>(&Bs[col][kc * 8]) = v;
        }
        __syncthreads();
        short8 a[4], b[4];
        #pragma unroll
        for (int m = 0; m < 4; ++m)
            a[m] = *reinterpret_cast<const short8*>(&As[wr * 64 + m * 16 + ar][kg * 8]);
        #pragma unroll
        for (int n = 0; n < 4; ++n)
            b[n] = *reinterpret_cast<const short8*>(&Bs[wc * 64 + n * 16 + ar][kg * 8]);
        #pragma unroll
        for (int m = 0; m < 4; ++m)
            #pragma unroll
            for (int n = 0; n < 4; ++n)
                acc[m][n] = __builtin_amdgcn_mfma_f32_16x16x32_bf16(a[m], b[n], acc[m][n], 0, 0, 0);
        __syncthreads();
    }

    // stage-1 epilogue: bias + relu, h-tile -> LDS bf16
    int rq = lane >> 4, cl = lane & 15;
    #pragma unroll
    for (int n = 0; n < 4; ++n) {
        int col = wc * 64 + n * 16 + cl;
        float bb = b2[col];
        #pragma unroll
        for (int m = 0; m < 4; ++m)
            #pragma unroll
            for (int r = 0; r < 4; ++r)
                hS[wr * 64 + m * 16 + rq * 4 + r][col] = f2b(fmaxf(acc[m][n][r] + bb, 0.f));
    }
    __syncthreads();

    // stage 2: rows [wave*16, +16) of z = h @ W3 (48 cols computed, 40 stored)
    f32x4 acc2[3];
    #pragma unroll
    for (int n = 0; n < 3; ++n) acc2[n] = (f32x4){0.f, 0.f, 0.f, 0.f};
    for (int k0 = 0; k0 < 256; k0 += 32) {
        short8 a = *reinterpret_cast<const short8*>(&hS[wave * 16 + ar][k0 + kg * 8]);
        #pragma unroll
        for (int n = 0; n < 3; ++n) {
            short8 b = *reinterpret_cast<const short8*>(&W3s[n * 16 + ar][k0 + kg * 8]);
            acc2[n] = __builtin_amdgcn_mfma_f32_16x16x32_bf16(a, b, acc2[n], 0, 0, 0);
        }
    }
    #pragma unroll
    for (int n = 0; n < 3; ++n) {
        int col = n * 16 + cl;
        if (col >= DOUT) continue;
        #pragma unroll
        for (int r = 0; r < 4; ++r) {
            int row = rowBase + wave * 16 + rq * 4 + r;
            if (row < M) Z[(size_t)row * DOUT + col] = f2b(acc2[n][r]);
        }
    }
}

// ---------------- SpMM D=40 (bf16 in) fused with +b3 and log_softmax ----------------
__global__ __launch_bounds__(256) void k_spmm40_lsm(const unsigned short* __restrict__ y,
                                                    const int* __restrict__ offs,
                                                    const int* __restrict__ csr_src,
                                                    const float* __restrict__ csr_w,
                                                    const float* __restrict__ inv_in,
                                                    const float* __restrict__ b3,
                                                    float* __restrict__ out, int n) {
    int wid = (blockIdx.x * 256 + threadIdx.x) >> 6;
    int lane = threadIdx.x & 63;
    if (wid >= n) return;
    int beg = offs[wid], end = offs[wid + 1];
    float acc = 0.f;
    int j = beg;
    for (; j + 4 <= end; j += 4) {
        int s0 = csr_src[j], s1 = csr_src[j + 1], s2 = csr_src[j + 2], s3 = csr_src[j + 3];
        float w0 = csr_w[j], w1 = csr_w[j + 1], w2 = csr_w[j + 2], w3 = csr_w[j + 3];
        float v0 = b2f(y[(size_t)s0 * DOUT + lane]);
        float v1 = b2f(y[(size_t)s1 * DOUT + lane]);
        float v2 = b2f(y[(size_t)s2 * DOUT + lane]);
        float v3 = b2f(y[(size_t)s3 * DOUT + lane]);
        acc += w0 * v0 + w1 * v1 + w2 * v2 + w3 * v3;
    }
    for (; j < end; ++j) {
        int s = csr_src[j];
        acc += csr_w[j] * b2f(y[(size_t)s * DOUT + lane]);
    }
    bool act = lane < DOUT;
    float v = act ? fmaf(inv_in[wid], acc, b3[lane]) : -INFINITY;
    float m = v;
    #pragma unroll
    for (int o = 32; o > 0; o >>= 1) m = fmaxf(m, __shfl_xor(m, o));
    float e = act ? __expf(v - m) : 0.f;
    float ssum = e;
    #pragma unroll
    for (int o = 32; o > 0; o >>= 1) ssum += __shfl_xor(ssum, o);
    float ls = logf(ssum);
    if (act) out[(size_t)wid * DOUT + lane] = v - m - ls;
}

extern "C" void kernel_launch(void* const* d_in, const int* in_sizes, int n_in,
                              void* d_out, int out_size, void* d_ws, size_t ws_size,
                              hipStream_t stream) {
    const float* x  = (const float*)d_in[0];
    const float* W1 = (const float*)d_in[1];
    const float* b1 = (const float*)d_in[2];
    const float* W2 = (const float*)d_in[3];
    const float* b2 = (const float*)d_in[4];
    const float* W3 = (const float*)d_in[5];
    const float* b3 = (const float*)d_in[6];
    const int* src  = (const int*)d_in[7];
    const int* dst  = (const int*)d_in[8];
    const int N = in_sizes[0] / D;   // 100000
    const int E = in_sizes[7];       // 1600000
    float* out = (float*)d_out;

    // workspace (~195 MB)
    char* p = (char*)d_ws;
    auto alloc = [&](size_t bytes) {
        char* r = p;
        p += (bytes + 255) & ~(size_t)255;
        return r;
    };
    unsigned* inH  = (unsigned*)alloc((size_t)HB * N * sizeof(unsigned));  // 12.8 MB
    unsigned* outH = (unsigned*)alloc((size_t)HB * N * sizeof(unsigned));  // 12.8 MB
    int*   indeg   = (int*)alloc((size_t)N * sizeof(int));
    int*   offs    = (int*)alloc((size_t)(N + 1) * sizeof(int));
    int*   bsum    = (int*)alloc((size_t)1024 * sizeof(int));
    int*   csr_src = (int*)alloc((size_t)E * sizeof(int));
    float* inv_out = (float*)alloc((size_t)N * sizeof(float));
    float* inv_in  = (float*)alloc((size_t)N * sizeof(float));
    float* csr_w   = (float*)alloc((size_t)E * sizeof(float));
    unsigned short* Wt1 = (unsigned short*)alloc((size_t)256 * 256 * 2);
    unsigned short* Wt2 = (unsigned short*)alloc((size_t)256 * 256 * 2);
    unsigned short* Wt3 = (unsigned short*)alloc((size_t)64 * 256 * 2);
    unsigned short* buf0 = (unsigned short*)alloc((size_t)N * D * 2);  // xb -> agg2
    unsigned short* buf1 = (unsigned short*)alloc((size_t)N * D * 2);  // agg1 -> z40
    unsigned short* buf2 = (unsigned short*)alloc((size_t)N * D * 2);  // h1

    // graph preprocessing (no device-scope atomics)
    k_hist<<<HB, 1024, 0, stream>>>(src, dst, inH, outH, N, E);
    k_colred<<<(N + 255) / 256, 256, 0, stream>>>(inH, outH, indeg, inv_in, inv_out, N);
    int G = (N + 1023) / 1024;
    k_scan1<<<G, 1024, 0, stream>>>(indeg, offs, bsum, N);
    k_scan2<<<1, 64, 0, stream>>>(bsum, G);
    k_scan3<<<G, 1024, 0, stream>>>(offs, bsum, N, E);
    k_scatter2<<<HB, 1024, 0, stream>>>(src, dst, offs, inH, inv_out, csr_src, csr_w, N, E);

    // weight conversion (tiny)
    k_cvt_wt<<<256, 256, 0, stream>>>(W1, Wt1);
    k_cvt_wt<<<256, 256, 0, stream>>>(W2, Wt2);
    k_cvt_wt3<<<64, 256, 0, stream>>>(W3, Wt3);

    // x -> bf16
    long long n8 = (long long)N * D / 8;
    k_cvt_x<<<(int)((n8 + 255) / 256), 256, 0, stream>>>(x, buf0, n8);

    dim3 gemmGrid((N + 127) / 128, 2);
    // layer 1
    k_spmm256b<<<(N + 3) / 4, 256, 0, stream>>>(buf0, offs, csr_src, csr_w, inv_in, buf1, N);
    k_gemm_mfma<<<gemmGrid, 256, 0, stream>>>(buf1, Wt1, b1, buf2, N);
    // layer 2 aggregate, then fused (layer-2 GEMM + relu + layer-3 GEMM)
    k_spmm256b<<<(N + 3) / 4, 256, 0, stream>>>(buf2, offs, csr_src, csr_w, inv_in, buf0, N);
    k_gemm_fuse23<<<(N + 127) / 128, 512, 0, stream>>>(buf0, Wt2, b2, Wt3, buf1, N);
    // layer 3: out = lsm(norm-SpMM(z40) + b3)
    k_spmm40_lsm<<<(N + 3) / 4, 256, 0, stream>>>(buf1, offs, csr_src, csr_w, inv_in,
                                                  b3, out, N);
}

// Round 6
// 740.494 us; speedup vs baseline: 1.6389x; 1.6389x over previous
//
#include <hip/hip_runtime.h>
#include <hip/hip_bf16.h>
#include <math.h>

#define D 256
#define DOUT 40

typedef __attribute__((ext_vector_type(8))) short short8;
typedef __attribute__((ext_vector_type(4))) float f32x4;

__device__ __forceinline__ float lo_bf(unsigned w) {
    union { unsigned u; float f; } c; c.u = w << 16; return c.f;
}
__device__ __forceinline__ float hi_bf(unsigned w) {
    union { unsigned u; float f; } c; c.u = w & 0xffff0000u; return c.f;
}
__device__ __forceinline__ float b2f(unsigned short u) {
    union { unsigned u; float f; } c; c.u = ((unsigned)u) << 16; return c.f;
}
__device__ __forceinline__ unsigned short f2b(float f) {
    __hip_bfloat16 h = __float2bfloat16(f);   // RNE
    return reinterpret_cast<unsigned short&>(h);
}

// ---------------- degree histogram + per-edge rank (device atomics) ----------------
__global__ __launch_bounds__(256) void k_degree(const int* __restrict__ src,
                                                const int* __restrict__ dst,
                                                int* __restrict__ outdeg,
                                                int* __restrict__ indeg,
                                                int* __restrict__ erank, int E) {
    int e = blockIdx.x * 256 + threadIdx.x;
    if (e < E) {
        atomicAdd(&outdeg[src[e]], 1);
        erank[e] = atomicAdd(&indeg[dst[e]], 1);
    }
}

// ---------------- inv-sqrt norm factors ----------------
__global__ __launch_bounds__(256) void k_invsqrt(const int* __restrict__ outdeg,
                                                 const int* __restrict__ indeg,
                                                 float* __restrict__ inv_out,
                                                 float* __restrict__ inv_in, int n) {
    int i = blockIdx.x * 256 + threadIdx.x;
    if (i < n) {
        int od = outdeg[i], idg = indeg[i];
        inv_out[i] = od > 0 ? rsqrtf((float)od) : 0.0f;
        inv_in[i]  = idg > 0 ? rsqrtf((float)idg) : 0.0f;
    }
}

// ---------------- hierarchical exclusive scan ----------------
__global__ __launch_bounds__(1024) void k_scan1(const int* __restrict__ deg,
                                                int* __restrict__ offs,
                                                int* __restrict__ bsum, int n) {
    __shared__ int wsum[16];
    int tid = threadIdx.x, lane = tid & 63, wv = tid >> 6;
    int i = blockIdx.x * 1024 + tid;
    int v = (i < n) ? deg[i] : 0;
    int x = v;
    #pragma unroll
    for (int o = 1; o < 64; o <<= 1) {
        int t = __shfl_up(x, o);
        if (lane >= o) x += t;
    }
    if (lane == 63) wsum[wv] = x;
    __syncthreads();
    if (wv == 0 && lane < 16) {
        int y = wsum[lane];
        #pragma unroll
        for (int o = 1; o < 16; o <<= 1) {
            int t = __shfl_up(y, o);
            if (lane >= o) y += t;
        }
        wsum[lane] = y;
    }
    __syncthreads();
    int waveoff = wv ? wsum[wv - 1] : 0;
    if (i < n) offs[i] = waveoff + x - v;
    if (tid == 0) bsum[blockIdx.x] = wsum[15];
}

__global__ __launch_bounds__(64) void k_scan2(int* __restrict__ bsum, int G) {
    int lane = threadIdx.x;
    int carry = 0;
    for (int base = 0; base < G; base += 64) {
        int idx = base + lane;
        int v = (idx < G) ? bsum[idx] : 0;
        int x = v;
        #pragma unroll
        for (int o = 1; o < 64; o <<= 1) {
            int t = __shfl_up(x, o);
            if (lane >= o) x += t;
        }
        int tot = __shfl(x, 63);
        if (idx < G) bsum[idx] = carry + x - v;
        carry += tot;
    }
}

__global__ __launch_bounds__(1024) void k_scan3(int* __restrict__ offs,
                                                const int* __restrict__ bsum,
                                                int n, int E) {
    int i = blockIdx.x * 1024 + threadIdx.x;
    if (i < n) offs[i] += bsum[blockIdx.x];
    if (i == 0) offs[n] = E;
}

// ---------------- atomic-free CSR scatter (uses precomputed ranks) ----------------
__global__ __launch_bounds__(256) void k_scatter3(const int* __restrict__ src,
                                                  const int* __restrict__ dst,
                                                  const int* __restrict__ erank,
                                                  const int* __restrict__ offs,
                                                  int* __restrict__ csr_src, int E) {
    int e = blockIdx.x * 256 + threadIdx.x;
    if (e < E) {
        int d = dst[e];
        csr_src[offs[d] + erank[e]] = src[e];
    }
}

// ---------------- f32 -> bf16 conversion of x, pre-scaled by inv_out[row] ----------------
__global__ __launch_bounds__(256) void k_cvt_x(const float* __restrict__ in,
                                               const float* __restrict__ inv_out,
                                               unsigned short* __restrict__ out,
                                               long long n8) {
    long long i = (long long)blockIdx.x * 256 + threadIdx.x;
    if (i >= n8) return;
    float s = inv_out[i >> 5];   // 8 floats/thread, 256/row -> row = i/32
    const float4* p = reinterpret_cast<const float4*>(in) + i * 2;
    float4 a = p[0], b = p[1];
    uint4 o;
    o.x = (unsigned)f2b(a.x * s) | ((unsigned)f2b(a.y * s) << 16);
    o.y = (unsigned)f2b(a.z * s) | ((unsigned)f2b(a.w * s) << 16);
    o.z = (unsigned)f2b(b.x * s) | ((unsigned)f2b(b.y * s) << 16);
    o.w = (unsigned)f2b(b.z * s) | ((unsigned)f2b(b.w * s) << 16);
    reinterpret_cast<uint4*>(out)[i] = o;
}

// ---------------- W[256,256] f32 -> Wt[n][k] bf16 ----------------
__global__ __launch_bounds__(256) void k_cvt_wt(const float* __restrict__ W,
                                                unsigned short* __restrict__ Wt) {
    int n = blockIdx.x, k = threadIdx.x;
    Wt[n * 256 + k] = f2b(W[k * 256 + n]);
}

// ---------------- W3[256,40] f32 -> Wt3[64 pad][256] bf16 ----------------
__global__ __launch_bounds__(256) void k_cvt_wt3(const float* __restrict__ W3,
                                                 unsigned short* __restrict__ Wt3) {
    int n = blockIdx.x, k = threadIdx.x;
    float v = (n < DOUT) ? W3[k * DOUT + n] : 0.0f;
    Wt3[n * 256 + k] = f2b(v);
}

// ---------------- SpMM bf16, D=256: unweighted gather-sum, x inv_in[dst] ----------------
__global__ __launch_bounds__(256) void k_spmm256b(const unsigned short* __restrict__ h,
                                                  const int* __restrict__ offs,
                                                  const int* __restrict__ csr_src,
                                                  const float* __restrict__ inv_in,
                                                  unsigned short* __restrict__ out, int n) {
    int wid = (blockIdx.x * 256 + threadIdx.x) >> 6;
    int lane = threadIdx.x & 63;
    if (wid >= n) return;
    int beg = offs[wid], end = offs[wid + 1];
    float a0 = 0.f, a1 = 0.f, a2 = 0.f, a3 = 0.f;
    int j = beg;
    for (; j + 8 <= end; j += 8) {
        int s[8]; uint2 v[8];
        #pragma unroll
        for (int q = 0; q < 8; ++q) s[q] = csr_src[j + q];
        #pragma unroll
        for (int q = 0; q < 8; ++q)
            v[q] = reinterpret_cast<const uint2*>(h + (size_t)s[q] * D)[lane];
        #pragma unroll
        for (int q = 0; q < 8; ++q) {
            a0 += lo_bf(v[q].x); a1 += hi_bf(v[q].x);
            a2 += lo_bf(v[q].y); a3 += hi_bf(v[q].y);
        }
    }
    for (; j < end; ++j) {
        int s = csr_src[j];
        uint2 v = reinterpret_cast<const uint2*>(h + (size_t)s * D)[lane];
        a0 += lo_bf(v.x); a1 += hi_bf(v.x); a2 += lo_bf(v.y); a3 += hi_bf(v.y);
    }
    float sc = inv_in[wid];
    uint2 r;
    r.x = (unsigned)f2b(sc * a0) | ((unsigned)f2b(sc * a1) << 16);
    r.y = (unsigned)f2b(sc * a2) | ((unsigned)f2b(sc * a3) << 16);
    reinterpret_cast<uint2*>(out + (size_t)wid * D)[lane] = r;
}

// ---- bf16 MFMA GEMM: C[M,256] = relu(A@Wt^T + b) * inv_out[row]  (pre-scaled out) ----
__global__ __launch_bounds__(256) void k_gemm_mfma(const unsigned short* __restrict__ A,
                                                   const unsigned short* __restrict__ Wt,
                                                   const float* __restrict__ bias,
                                                   const float* __restrict__ inv_out,
                                                   unsigned short* __restrict__ C, int M) {
    __shared__ unsigned short As[128][40];
    __shared__ unsigned short Bs[128][40];
    int tid = threadIdx.x;
    int lane = tid & 63, wave = tid >> 6;
    int wr = wave >> 1, wc = wave & 1;
    int rowBase = blockIdx.x * 128;
    int colBase = blockIdx.y * 128;

    f32x4 acc[4][4];
    #pragma unroll
    for (int m = 0; m < 4; ++m)
        #pragma unroll
        for (int n = 0; n < 4; ++n) acc[m][n] = (f32x4){0.f, 0.f, 0.f, 0.f};

    int ar = lane & 15, kg = lane >> 4;

    for (int k0 = 0; k0 < 256; k0 += 32) {
        #pragma unroll
        for (int hh = 0; hh < 2; ++hh) {
            int c = tid + hh * 256;
            int row = c >> 2, kc = c & 3;
            int grow = rowBase + row;
            uint4 v = make_uint4(0, 0, 0, 0);
            if (grow < M)
                v = *reinterpret_cast<const uint4*>(A + (size_t)grow * 256 + k0 + kc * 8);
            *reinterpret_cast<uint4*>(&As[row][kc * 8]) = v;
        }
        #pragma unroll
        for (int hh = 0; hh < 2; ++hh) {
            int c = tid + hh * 256;
            int col = c >> 2, kc = c & 3;
            uint4 v = *reinterpret_cast<const uint4*>(Wt + (size_t)(colBase + col) * 256 + k0 + kc * 8);
            *reinterpret_cast<uint4*>(&Bs[col][kc * 8]) = v;
        }
        __syncthreads();
        short8 a[4], b[4];
        #pragma unroll
        for (int m = 0; m < 4; ++m)
            a[m] = *reinterpret_cast<const short8*>(&As[wr * 64 + m * 16 + ar][kg * 8]);
        #pragma unroll
        for (int n = 0; n < 4; ++n)
            b[n] = *reinterpret_cast<const short8*>(&Bs[wc * 64 + n * 16 + ar][kg * 8]);
        #pragma unroll
        for (int m = 0; m < 4; ++m)
            #pragma unroll
            for (int n = 0; n < 4; ++n)
                acc[m][n] = __builtin_amdgcn_mfma_f32_16x16x32_bf16(a[m], b[n], acc[m][n], 0, 0, 0);
        __syncthreads();
    }

    int rq = lane >> 4, cl = lane & 15;
    float bv[4];
    #pragma unroll
    for (int n = 0; n < 4; ++n) bv[n] = bias[colBase + wc * 64 + n * 16 + cl];
    #pragma unroll
    for (int m = 0; m < 4; ++m) {
        int row0 = rowBase + wr * 64 + m * 16 + rq * 4;
        #pragma unroll
        for (int r = 0; r < 4; ++r) {
            int row = row0 + r;
            if (row >= M) continue;
            float so = inv_out[row];
            #pragma unroll
            for (int n = 0; n < 4; ++n) {
                int col = colBase + wc * 64 + n * 16 + cl;
                C[(size_t)row * 256 + col] = f2b(fmaxf(acc[m][n][r] + bv[n], 0.f) * so);
            }
        }
    }
}

// ---- fused layers 2+3: z[M,40] = (relu(A@W2t^T + b2) @ W3) * inv_out[row] ----
__global__ __launch_bounds__(512) void k_gemm_fuse23(const unsigned short* __restrict__ A,
                                                     const unsigned short* __restrict__ Wt2,
                                                     const float* __restrict__ b2,
                                                     const unsigned short* __restrict__ Wt3,
                                                     const float* __restrict__ inv_out,
                                                     unsigned short* __restrict__ Z, int M) {
    __shared__ unsigned short As[128][40];
    __shared__ unsigned short Bs[256][40];
    __shared__ unsigned short hS[128][264];
    __shared__ unsigned short W3s[64][264];
    int tid = threadIdx.x;
    int lane = tid & 63, wave = tid >> 6;
    int wr = wave >> 2, wc = wave & 3;
    int rowBase = blockIdx.x * 128;
    int ar = lane & 15, kg = lane >> 4;

    for (int c = tid; c < 2048; c += 512) {
        int row = c >> 5, kc = c & 31;
        *reinterpret_cast<uint4*>(&W3s[row][kc * 8]) =
            *reinterpret_cast<const uint4*>(Wt3 + (size_t)row * 256 + kc * 8);
    }

    f32x4 acc[4][4];
    #pragma unroll
    for (int m = 0; m < 4; ++m)
        #pragma unroll
        for (int n = 0; n < 4; ++n) acc[m][n] = (f32x4){0.f, 0.f, 0.f, 0.f};

    for (int k0 = 0; k0 < 256; k0 += 32) {
        {
            int row = tid >> 2, kc = tid & 3;
            int grow = rowBase + row;
            uint4 v = make_uint4(0, 0, 0, 0);
            if (grow < M)
                v = *reinterpret_cast<const uint4*>(A + (size_t)grow * 256 + k0 + kc * 8);
            *reinterpret_cast<uint4*>(&As[row][kc * 8]) = v;
        }
        #pragma unroll
        for (int hh = 0; hh < 2; ++hh) {
            int c = tid + hh * 512;
            int col = c >> 2, kc = c & 3;
            uint4 v = *reinterpret_cast<const uint4*>(Wt2 + (size_t)col * 256 + k0 + kc * 8);
            *reinterpret_cast<uint4*>(&Bs[col][kc * 8]) = v;
        }
        __syncthreads();
        short8 a[4], b[4];
        #pragma unroll
        for (int m = 0; m < 4; ++m)
            a[m] = *reinterpret_cast<const short8*>(&As[wr * 64 + m * 16 + ar][kg * 8]);
        #pragma unroll
        for (int n = 0; n < 4; ++n)
            b[n] = *reinterpret_cast<const short8*>(&Bs[wc * 64 + n * 16 + ar][kg * 8]);
        #pragma unroll
        for (int m = 0; m < 4; ++m)
            #pragma unroll
            for (int n = 0; n < 4; ++n)
                acc[m][n] = __builtin_amdgcn_mfma_f32_16x16x32_bf16(a[m], b[n], acc[m][n], 0, 0, 0);
        __syncthreads();
    }

    int rq = lane >> 4, cl = lane & 15;
    #pragma unroll
    for (int n = 0; n < 4; ++n) {
        int col = wc * 64 + n * 16 + cl;
        float bb = b2[col];
        #pragma unroll
        for (int m = 0; m < 4; ++m)
            #pragma unroll
            for (int r = 0; r < 4; ++r)
                hS[wr * 64 + m * 16 + rq * 4 + r][col] = f2b(fmaxf(acc[m][n][r] + bb, 0.f));
    }
    __syncthreads();

    f32x4 acc2[3];
    #pragma unroll
    for (int n = 0; n < 3; ++n) acc2[n] = (f32x4){0.f, 0.f, 0.f, 0.f};
    for (int k0 = 0; k0 < 256; k0 += 32) {
        short8 a = *reinterpret_cast<const short8*>(&hS[wave * 16 + ar][k0 + kg * 8]);
        #pragma unroll
        for (int n = 0; n < 3; ++n) {
            short8 b = *reinterpret_cast<const short8*>(&W3s[n * 16 + ar][k0 + kg * 8]);
            acc2[n] = __builtin_amdgcn_mfma_f32_16x16x32_bf16(a, b, acc2[n], 0, 0, 0);
        }
    }
    #pragma unroll
    for (int r = 0; r < 4; ++r) {
        int row = rowBase + wave * 16 + rq * 4 + r;
        if (row >= M) continue;
        float so = inv_out[row];
        #pragma unroll
        for (int n = 0; n < 3; ++n) {
            int col = n * 16 + cl;
            if (col < DOUT) Z[(size_t)row * DOUT + col] = f2b(acc2[n][r] * so);
        }
    }
}

// ---------------- SpMM D=40 (pre-scaled bf16 in) + b3 + log_softmax ----------------
__global__ __launch_bounds__(256) void k_spmm40_lsm(const unsigned short* __restrict__ y,
                                                    const int* __restrict__ offs,
                                                    const int* __restrict__ csr_src,
                                                    const float* __restrict__ inv_in,
                                                    const float* __restrict__ b3,
                                                    float* __restrict__ out, int n) {
    int wid = (blockIdx.x * 256 + threadIdx.x) >> 6;
    int lane = threadIdx.x & 63;
    if (wid >= n) return;
    int beg = offs[wid], end = offs[wid + 1];
    float acc = 0.f;
    int j = beg;
    for (; j + 4 <= end; j += 4) {
        int s0 = csr_src[j], s1 = csr_src[j + 1], s2 = csr_src[j + 2], s3 = csr_src[j + 3];
        float v0 = b2f(y[(size_t)s0 * DOUT + lane]);
        float v1 = b2f(y[(size_t)s1 * DOUT + lane]);
        float v2 = b2f(y[(size_t)s2 * DOUT + lane]);
        float v3 = b2f(y[(size_t)s3 * DOUT + lane]);
        acc += v0 + v1 + v2 + v3;
    }
    for (; j < end; ++j) {
        int s = csr_src[j];
        acc += b2f(y[(size_t)s * DOUT + lane]);
    }
    bool act = lane < DOUT;
    float v = act ? fmaf(inv_in[wid], acc, b3[lane]) : -INFINITY;
    float m = v;
    #pragma unroll
    for (int o = 32; o > 0; o >>= 1) m = fmaxf(m, __shfl_xor(m, o));
    float e = act ? __expf(v - m) : 0.f;
    float ssum = e;
    #pragma unroll
    for (int o = 32; o > 0; o >>= 1) ssum += __shfl_xor(ssum, o);
    float ls = logf(ssum);
    if (act) out[(size_t)wid * DOUT + lane] = v - m - ls;
}

extern "C" void kernel_launch(void* const* d_in, const int* in_sizes, int n_in,
                              void* d_out, int out_size, void* d_ws, size_t ws_size,
                              hipStream_t stream) {
    const float* x  = (const float*)d_in[0];
    const float* W1 = (const float*)d_in[1];
    const float* b1 = (const float*)d_in[2];
    const float* W2 = (const float*)d_in[3];
    const float* b2 = (const float*)d_in[4];
    const float* W3 = (const float*)d_in[5];
    const float* b3 = (const float*)d_in[6];
    const int* src  = (const int*)d_in[7];
    const int* dst  = (const int*)d_in[8];
    const int N = in_sizes[0] / D;   // 100000
    const int E = in_sizes[7];       // 1600000
    float* out = (float*)d_out;

    // workspace (~180 MB)
    char* p = (char*)d_ws;
    auto alloc = [&](size_t bytes) {
        char* r = p;
        p += (bytes + 255) & ~(size_t)255;
        return r;
    };
    int*   zeroz   = (int*)alloc((size_t)2 * N * sizeof(int));  // outdeg | indeg
    int*   erank   = (int*)alloc((size_t)E * sizeof(int));
    int*   offs    = (int*)alloc((size_t)(N + 1) * sizeof(int));
    int*   bsum    = (int*)alloc((size_t)1024 * sizeof(int));
    int*   csr_src = (int*)alloc((size_t)E * sizeof(int));
    float* inv_out = (float*)alloc((size_t)N * sizeof(float));
    float* inv_in  = (float*)alloc((size_t)N * sizeof(float));
    unsigned short* Wt1 = (unsigned short*)alloc((size_t)256 * 256 * 2);
    unsigned short* Wt2 = (unsigned short*)alloc((size_t)256 * 256 * 2);
    unsigned short* Wt3 = (unsigned short*)alloc((size_t)64 * 256 * 2);
    unsigned short* buf0 = (unsigned short*)alloc((size_t)N * D * 2);  // xb -> agg2
    unsigned short* buf1 = (unsigned short*)alloc((size_t)N * D * 2);  // agg1 -> z40
    unsigned short* buf2 = (unsigned short*)alloc((size_t)N * D * 2);  // h1
    int* outdeg = zeroz;
    int* indeg  = zeroz + N;

    // graph preprocessing
    hipMemsetAsync(zeroz, 0, (size_t)2 * N * sizeof(int), stream);
    k_degree<<<(E + 255) / 256, 256, 0, stream>>>(src, dst, outdeg, indeg, erank, E);
    k_invsqrt<<<(N + 255) / 256, 256, 0, stream>>>(outdeg, indeg, inv_out, inv_in, N);
    int G = (N + 1023) / 1024;
    k_scan1<<<G, 1024, 0, stream>>>(indeg, offs, bsum, N);
    k_scan2<<<1, 64, 0, stream>>>(bsum, G);
    k_scan3<<<G, 1024, 0, stream>>>(offs, bsum, N, E);
    k_scatter3<<<(E + 255) / 256, 256, 0, stream>>>(src, dst, erank, offs, csr_src, E);

    // weight conversion (tiny)
    k_cvt_wt<<<256, 256, 0, stream>>>(W1, Wt1);
    k_cvt_wt<<<256, 256, 0, stream>>>(W2, Wt2);
    k_cvt_wt3<<<64, 256, 0, stream>>>(W3, Wt3);

    // x -> bf16, pre-scaled by inv_out
    long long n8 = (long long)N * D / 8;
    k_cvt_x<<<(int)((n8 + 255) / 256), 256, 0, stream>>>(x, inv_out, buf0, n8);

    dim3 gemmGrid((N + 127) / 128, 2);
    // layer 1
    k_spmm256b<<<(N + 3) / 4, 256, 0, stream>>>(buf0, offs, csr_src, inv_in, buf1, N);
    k_gemm_mfma<<<gemmGrid, 256, 0, stream>>>(buf1, Wt1, b1, inv_out, buf2, N);
    // layer 2 aggregate, then fused (layer-2 GEMM + relu + layer-3 GEMM)
    k_spmm256b<<<(N + 3) / 4, 256, 0, stream>>>(buf2, offs, csr_src, inv_in, buf0, N);
    k_gemm_fuse23<<<(N + 127) / 128, 512, 0, stream>>>(buf0, Wt2, b2, Wt3, inv_out, buf1, N);
    // layer 3: out = lsm(norm-SpMM(z40) + b3)
    k_spmm40_lsm<<<(N + 3) / 4, 256, 0, stream>>>(buf1, offs, csr_src, inv_in, b3, out, N);
}